// Round 8
// baseline (323.814 us; speedup 1.0000x reference)
//
#include <hip/hip_runtime.h>
#include <math.h>

#define NB 4
#define NPI 12000
#define NM 32
#define NPTS (NB*NPI*NM)      // 1536000
#define NPIL (NB*NPI)         // 48000

// k_moments config
#define K1_BLOCKS 1500
#define K1_STRIDE (K1_BLOCKS*256)   // 384000
#define K1_ITERS 4                  // NPTS / K1_STRIDE
#define NMOM 55                     // 9 Sf + 45 Sff + 1 valid-count

// heavy-kernel config: 128 points (4 sorted pillars) per batch
#define CHUNK 128
#define NBATCH (NPTS/CHUNK)   // 12000
#define SB 1024               // grid for k_stats2
#define LDH 68                // padded h1 row stride (floats)

// sort config
#define SLICE 188             // 256*188 = 48128 >= NPIL

// ---------------------------------------------------------------- helpers

__device__ __forceinline__ void make_f(float4 v, int4 cc, int np, int m, float zc, float f[9]) {
  const float cx = ((float)cc.w + 0.5f) * 0.16f + 0.0f;
  const float cy = ((float)cc.z + 0.5f) * 0.16f - 39.68f;
  f[0] = v.x; f[1] = v.y; f[2] = v.z; f[3] = v.w;
  f[4] = v.x - cx; f[5] = v.y - cy; f[6] = cx; f[7] = cy; f[8] = zc;
  const float msk = (m < np) ? 1.0f : 0.0f;
#pragma unroll
  for (int i = 0; i < 9; ++i) f[i] *= msk;
}

// ------------------------------------------------- K0: stable counting sort of
// pillars by np (33 bins). Single block, deterministic.

__global__ __launch_bounds__(256) void k_sort(
    const int* __restrict__ npnts, int* __restrict__ perm) {
  __shared__ int C[33][256];
  __shared__ int T[33], O[33];
  const int t = threadIdx.x;
#pragma unroll
  for (int b = 0; b < 33; ++b) C[b][t] = 0;
  __syncthreads();
  const int i0 = t * SLICE;
  const int i1 = (i0 + SLICE < NPIL) ? i0 + SLICE : NPIL;
  for (int i = i0; i < i1; ++i) C[npnts[i]][t]++;
  __syncthreads();
  if (t < 33) { int s = 0; for (int j = 0; j < 256; ++j) s += C[t][j]; T[t] = s; }
  __syncthreads();
  if (t == 0) { int r = 0; for (int b = 0; b < 33; ++b) { O[b] = r; r += T[b]; } }
  __syncthreads();
  if (t < 33) {
    int r = O[t];
    for (int j = 0; j < 256; ++j) { const int c = C[t][j]; C[t][j] = r; r += c; }
  }
  __syncthreads();
  for (int i = i0; i < i1; ++i) {
    const int b = npnts[i];
    const int p = C[b][t];
    C[b][t] = p + 1;
    perm[p] = i;
  }
}

// ------------------------------------------------- K1: f-moments + valid count

__global__ __launch_bounds__(256) void k_moments(
    const float4* __restrict__ vox, const int4* __restrict__ coords,
    const int* __restrict__ npnts, float* __restrict__ P1) {
  const int t = blockIdx.x * 256 + threadIdx.x;
  float acc[NMOM];
#pragma unroll
  for (int v = 0; v < NMOM; ++v) acc[v] = 0.0f;

#pragma unroll
  for (int j = 0; j < K1_ITERS; ++j) {
    const int pt = t + j * K1_STRIDE;
    const int pil = pt >> 5;
    const int m = pt & 31;
    const float4 v = vox[pt];
    const int4 cc = coords[pil];
    const int np = npnts[pil];
    float z = v.z;
#pragma unroll
    for (int s = 1; s < 32; s <<= 1) z += __shfl_xor(z, s, 32);
    const float zc = z * (1.0f / 32.0f);
    float f[9];
    make_f(v, cc, np, m, zc, f);
    int vi = 0;
#pragma unroll
    for (int i = 0; i < 9; ++i) acc[vi++] += f[i];
#pragma unroll
    for (int i = 0; i < 9; ++i)
#pragma unroll
      for (int jj = i; jj < 9; ++jj) acc[vi++] += f[i] * f[jj];
    acc[54] += (m < np) ? 1.0f : 0.0f;
  }

#pragma unroll
  for (int v = 0; v < NMOM; ++v) {
    float x = acc[v];
#pragma unroll
    for (int s = 1; s < 64; s <<= 1) x += __shfl_xor(x, s, 64);
    acc[v] = x;
  }
  __shared__ float red[4][NMOM];
  const int wave = threadIdx.x >> 6, lane = threadIdx.x & 63;
  if (lane == 0) {
#pragma unroll
    for (int v = 0; v < NMOM; ++v) red[wave][v] = acc[v];
  }
  __syncthreads();
  if (threadIdx.x < NMOM) {
    float s = red[0][threadIdx.x] + red[1][threadIdx.x] + red[2][threadIdx.x] + red[3][threadIdx.x];
    P1[threadIdx.x * K1_BLOCKS + blockIdx.x] = s;
  }
}

// ------------------------------------------------- generic row reduce (f32 -> f64)

__global__ __launch_bounds__(256) void k_rowreduce(
    const float* __restrict__ src, double* __restrict__ dst, int ncols) {
  const int row = blockIdx.x;
  const float* p = src + row * ncols;
  double sd = 0.0;
  for (int i = threadIdx.x; i < ncols; i += 256) sd += (double)p[i];
#pragma unroll
  for (int s = 1; s < 64; s <<= 1) sd += __shfl_xor(sd, s, 64);
  __shared__ double rd[4];
  const int wave = threadIdx.x >> 6, lane = threadIdx.x & 63;
  if (lane == 0) rd[wave] = sd;
  __syncthreads();
  if (threadIdx.x == 0) dst[row] = rd[0] + rd[1] + rd[2] + rd[3];
}

// ------------------------------------------------- finalize layer-1 BN params

__global__ void k_fin1(const double* __restrict__ T1, const float* __restrict__ W1,
                       const float* __restrict__ g1, const float* __restrict__ b1,
                       float* __restrict__ params) {
  const int c = threadIdx.x;  // 64
  double w[9];
#pragma unroll
  for (int i = 0; i < 9; ++i) w[i] = (double)W1[i * 64 + c];
  double mean = 0.0;
#pragma unroll
  for (int i = 0; i < 9; ++i) mean += w[i] * T1[i];
  mean /= (double)NPTS;
  double e2 = 0.0;
  int v = 9;
#pragma unroll
  for (int i = 0; i < 9; ++i)
#pragma unroll
    for (int j = i; j < 9; ++j) {
      const double t = T1[v++] * w[i] * w[j];
      e2 += (i == j) ? t : 2.0 * t;
    }
  e2 /= (double)NPTS;
  const double var = e2 - mean * mean;
  const double a = (double)g1[c] / sqrt(var + 0.001);
  params[c] = (float)a;
  params[64 + c] = (float)((double)b1[c] - mean * a);
}

// ------------------------------------------------- K3: layer-2 stats + y2 max/min
// __launch_bounds__(256,2): round 7 ran (256,4); the added ymx/ymn pushed
// pressure past the 128-VGPR cap and the allocator DEMOTED w2[64] to repeated
// cached W2 loads (VGPR_Count=60, +70us). Cap 256 keeps w2 resident; if the
// allocator lands <=128 the HW still runs 4 waves/EU (bounds cap allocation,
// not occupancy). Same fix as round 3's k_out.

__global__ __launch_bounds__(256, 2) void k_stats2(
    const float4* __restrict__ vox, const int4* __restrict__ coords,
    const int* __restrict__ npnts, const float* __restrict__ W1,
    const float* __restrict__ W2, const float* __restrict__ params,
    const int* __restrict__ perm, float* __restrict__ P2,
    float* __restrict__ Y2MAX, float* __restrict__ Y2MIN) {
  __shared__ __align__(16) float W1t[9 * 64];
  __shared__ __align__(16) float a1s[64], b1s[64];
  __shared__ __align__(16) float h1s[CHUNK * LDH];
  __shared__ float redS[4][64], redQ[4][64];

  const int t = threadIdx.x;
  for (int i = t; i < 576; i += 256) W1t[i] = W1[i];
  if (t < 64) { a1s[t] = params[t]; b1s[t] = params[64 + t]; }

  const int c = t & 63;
  float w2[64];
#pragma unroll
  for (int k = 0; k < 64; ++k) w2[k] = W2[k * 64 + c];
  __syncthreads();

  const int p_loc = t >> 1;
  const int ch_half = (t & 1) * 32;
  const int g = t >> 6;
  float psum = 0.0f, psq = 0.0f;

  for (int bb = blockIdx.x; bb < NBATCH; bb += SB) {
    // ---- phase A: h1 for 128 points (4 permuted pillars)
    const int pid = perm[bb * 4 + (p_loc >> 5)];
    const int m = p_loc & 31;
    const float4 v = vox[pid * 32 + m];
    const int4 cc = coords[pid];
    const int np = npnts[pid];
    float z = v.z;
#pragma unroll
    for (int s = 1; s < 64; s <<= 1) z += __shfl_xor(z, s, 64);
    const float zc = z * (1.0f / 64.0f);
    float f[9];
    make_f(v, cc, np, m, zc, f);
    float* row = &h1s[p_loc * LDH];
#pragma unroll
    for (int j = 0; j < 8; ++j) {
      const int c0 = ch_half + 4 * j;
      float y0 = 0, y1 = 0, y2 = 0, y3 = 0;
#pragma unroll
      for (int i = 0; i < 9; ++i) {
        const float4 w = *(const float4*)&W1t[i * 64 + c0];
        y0 = fmaf(f[i], w.x, y0);
        y1 = fmaf(f[i], w.y, y1);
        y2 = fmaf(f[i], w.z, y2);
        y3 = fmaf(f[i], w.w, y3);
      }
      const float4 a = *(const float4*)&a1s[c0];
      const float4 b = *(const float4*)&b1s[c0];
      float4 h;
      h.x = fmaxf(fmaf(y0, a.x, b.x), 0.0f);
      h.y = fmaxf(fmaf(y1, a.y, b.y), 0.0f);
      h.z = fmaxf(fmaf(y2, a.z, b.z), 0.0f);
      h.w = fmaxf(fmaf(y3, a.w, b.w), 0.0f);
      *(float4*)&row[c0] = h;
    }
    __syncthreads();
    // ---- phase B: valid points only; track running y2 max/min for this pillar
    const int pidB = perm[bb * 4 + g];
    const int np_g = npnts[pidB];
    float ymx = -INFINITY, ymn = INFINITY;
#pragma unroll 2
    for (int pp = 0; pp < np_g; ++pp) {
      const float4* hr = (const float4*)&h1s[(g * 32 + pp) * LDH];
      float y0 = 0, y1 = 0, y2 = 0, y3 = 0;
#pragma unroll
      for (int a4 = 0; a4 < 16; ++a4) {
        const float4 hv = hr[a4];   // broadcast read
        y0 = fmaf(hv.x, w2[4 * a4 + 0], y0);
        y1 = fmaf(hv.y, w2[4 * a4 + 1], y1);
        y2 = fmaf(hv.z, w2[4 * a4 + 2], y2);
        y3 = fmaf(hv.w, w2[4 * a4 + 3], y3);
      }
      const float y = (y0 + y1) + (y2 + y3);
      psum += y;
      psq = fmaf(y, y, psq);
      ymx = fmaxf(ymx, y);
      ymn = fminf(ymn, y);
    }
    Y2MAX[pidB * 64 + c] = ymx;   // coalesced (lane = channel)
    Y2MIN[pidB * 64 + c] = ymn;
    __syncthreads();
  }

  const int wave = t >> 6;
  redS[wave][c] = psum;
  redQ[wave][c] = psq;
  __syncthreads();
  if (t < 64) {
    const float s = redS[0][t] + redS[1][t] + redS[2][t] + redS[3][t];
    const float q = redQ[0][t] + redQ[1][t] + redQ[2][t] + redQ[3][t];
    P2[t * SB + blockIdx.x] = s;
    P2[(64 + t) * SB + blockIdx.x] = q;
  }
}

// ------------------------------------------------- finalize layer-2 BN params

__global__ void k_fin2(const double* __restrict__ T2, const float* __restrict__ g2,
                       const float* __restrict__ b2, const float* __restrict__ W2,
                       const double* __restrict__ T1, float* __restrict__ params) {
  const int c = threadIdx.x;  // 64
  const double nmask = (double)NPTS - T1[54];
  double y20 = 0.0;
  for (int k = 0; k < 64; ++k) {
    const float h0 = fmaxf(params[64 + k], 0.0f);   // h1_0[k] = relu(b1adj[k])
    y20 += (double)h0 * (double)W2[k * 64 + c];
  }
  const double sum = T2[c] + nmask * y20;
  const double sq  = T2[64 + c] + nmask * y20 * y20;
  const double mean = sum / (double)NPTS;
  const double var = sq / (double)NPTS - mean * mean;
  const double a = (double)g2[c] / sqrt(var + 0.001);
  const double badj = (double)b2[c] - mean * a;
  params[128 + c] = (float)a;
  params[192 + c] = (float)badj;
  params[256 + c] = (float)fmax(a * y20 + badj, 0.0);   // h2_0[c] (relu)
}

// ------------------------------------------------- K5: final output pass.
// h2 = relu(a2*y2 + b2adj) is monotone in y2 (direction = sign(a2)); fma/relu
// rounding is monotone, so max over points = the map applied to max(y2)
// (or min(y2) if a2<0) BIT-EXACTLY. Pure streaming pass, ~37 MB.

__global__ __launch_bounds__(256) void k_final(
    const int* __restrict__ npnts, const float* __restrict__ params,
    const float* __restrict__ Y2MAX, const float* __restrict__ Y2MIN,
    float* __restrict__ out) {
  const int idx = blockIdx.x * 256 + threadIdx.x;   // NPIL*64 total
  const int pid = idx >> 6;
  const int c = idx & 63;
  const int np = npnts[pid];
  const float a2 = params[128 + c];
  const float b2 = params[192 + c];
  const float h20 = params[256 + c];
  const float mx = Y2MAX[idx];
  const float mn = Y2MIN[idx];
  const float sel = (a2 >= 0.0f) ? mx : mn;
  float h = (np > 0) ? fmaxf(fmaf(sel, a2, b2), 0.0f) : 0.0f;
  if (np < 32) h = fmaxf(h, h20);
  out[idx] = h;
}

// ---------------------------------------------------------------- launch

extern "C" void kernel_launch(void* const* d_in, const int* in_sizes, int n_in,
                              void* d_out, int out_size, void* d_ws, size_t ws_size,
                              hipStream_t stream) {
  const float4* vox = (const float4*)d_in[0];
  const int4* coords = (const int4*)d_in[1];
  const int* npnts = (const int*)d_in[2];
  const float* W1 = (const float*)d_in[3];
  const float* g1 = (const float*)d_in[4];
  const float* b1 = (const float*)d_in[5];
  const float* W2 = (const float*)d_in[6];
  const float* g2 = (const float*)d_in[7];
  const float* b2 = (const float*)d_in[8];
  float* out = (float*)d_out;

  char* w = (char*)d_ws;
  size_t off = 0;
  double* T1 = (double*)(w + off); off += 512;                 // 55 doubles
  double* T2 = (double*)(w + off); off += 1024;                // 128 doubles
  float* P1 = (float*)(w + off); off += NMOM * K1_BLOCKS * 4;  // 330 KB
  float* P2 = (float*)(w + off); off += 128 * SB * 4;          // 524 KB
  float* params = (float*)(w + off); off += 512 * 4;           // 320 used
  int* perm = (int*)(w + off); off += NPIL * 4;                // 192 KB
  float* Y2MAX = (float*)(w + off); off += (size_t)NPIL * 64 * 4;  // 12.3 MB
  float* Y2MIN = (float*)(w + off); off += (size_t)NPIL * 64 * 4;  // 12.3 MB

  k_sort<<<1, 256, 0, stream>>>(npnts, perm);
  k_moments<<<K1_BLOCKS, 256, 0, stream>>>(vox, coords, npnts, P1);
  k_rowreduce<<<NMOM, 256, 0, stream>>>(P1, T1, K1_BLOCKS);
  k_fin1<<<1, 64, 0, stream>>>(T1, W1, g1, b1, params);
  k_stats2<<<SB, 256, 0, stream>>>(vox, coords, npnts, W1, W2, params, perm, P2, Y2MAX, Y2MIN);
  k_rowreduce<<<128, 256, 0, stream>>>(P2, T2, SB);
  k_fin2<<<1, 64, 0, stream>>>(T2, g2, b2, W2, T1, params);
  k_final<<<(NPIL * 64) / 256, 256, 0, stream>>>(npnts, params, Y2MAX, Y2MIN, out);
}

// Round 9
// 305.023 us; speedup vs baseline: 1.0616x; 1.0616x over previous
//
#include <hip/hip_runtime.h>
#include <math.h>

#define NB 4
#define NPI 12000
#define NM 32
#define NPTS (NB*NPI*NM)      // 1536000
#define NPIL (NB*NPI)         // 48000

// k_moments config
#define K1_BLOCKS 1500
#define K1_STRIDE (K1_BLOCKS*256)   // 384000
#define K1_ITERS 4                  // NPTS / K1_STRIDE
#define NMOM 55                     // 9 Sf + 45 Sff + 1 valid-count

// heavy-kernel config: 128 points (4 sorted pillars) per batch
#define CHUNK 128
#define NBATCH (NPTS/CHUNK)   // 12000
#define SB 1024               // grid for k_stats2
#define LDH 68                // padded h1 row stride (floats)

// sort config
#define SLICE 188             // 256*188 = 48128 >= NPIL

// ---------------------------------------------------------------- helpers

__device__ __forceinline__ void make_f(float4 v, int4 cc, int np, int m, float zc, float f[9]) {
  const float cx = ((float)cc.w + 0.5f) * 0.16f + 0.0f;
  const float cy = ((float)cc.z + 0.5f) * 0.16f - 39.68f;
  f[0] = v.x; f[1] = v.y; f[2] = v.z; f[3] = v.w;
  f[4] = v.x - cx; f[5] = v.y - cy; f[6] = cx; f[7] = cy; f[8] = zc;
  const float msk = (m < np) ? 1.0f : 0.0f;
#pragma unroll
  for (int i = 0; i < 9; ++i) f[i] *= msk;
}

// ------------------------------------------------- K0: stable counting sort of
// pillars by np (33 bins). Single block, deterministic. Round 9: global loads
// batched 8-wide so the serial {load->LDS RMW} chains pipeline; identical
// order of operations -> bit-identical perm.

__global__ __launch_bounds__(256) void k_sort(
    const int* __restrict__ npnts, int* __restrict__ perm) {
  __shared__ int C[33][256];
  __shared__ int T[33], O[33];
  const int t = threadIdx.x;
#pragma unroll
  for (int b = 0; b < 33; ++b) C[b][t] = 0;
  __syncthreads();
  const int i0 = t * SLICE;
  const int i1 = (i0 + SLICE < NPIL) ? i0 + SLICE : NPIL;
  {
    int i = i0;
    for (; i + 8 <= i1; i += 8) {
      int bs[8];
#pragma unroll
      for (int j = 0; j < 8; ++j) bs[j] = npnts[i + j];   // 8 loads in flight
#pragma unroll
      for (int j = 0; j < 8; ++j) C[bs[j]][t]++;
    }
    for (; i < i1; ++i) C[npnts[i]][t]++;
  }
  __syncthreads();
  if (t < 33) { int s = 0; for (int j = 0; j < 256; ++j) s += C[t][j]; T[t] = s; }
  __syncthreads();
  if (t == 0) { int r = 0; for (int b = 0; b < 33; ++b) { O[b] = r; r += T[b]; } }
  __syncthreads();
  if (t < 33) {
    int r = O[t];
    for (int j = 0; j < 256; ++j) { const int c = C[t][j]; C[t][j] = r; r += c; }
  }
  __syncthreads();
  {
    int i = i0;
    for (; i + 8 <= i1; i += 8) {
      int bs[8];
#pragma unroll
      for (int j = 0; j < 8; ++j) bs[j] = npnts[i + j];   // pipeline the loads
#pragma unroll
      for (int j = 0; j < 8; ++j) {
        const int b = bs[j];
        const int p = C[b][t];
        C[b][t] = p + 1;
        perm[p] = i + j;
      }
    }
    for (; i < i1; ++i) {
      const int b = npnts[i];
      const int p = C[b][t];
      C[b][t] = p + 1;
      perm[p] = i;
    }
  }
}

// ------------------------------------------------- K1: f-moments + valid count

__global__ __launch_bounds__(256) void k_moments(
    const float4* __restrict__ vox, const int4* __restrict__ coords,
    const int* __restrict__ npnts, float* __restrict__ P1) {
  const int t = blockIdx.x * 256 + threadIdx.x;
  float acc[NMOM];
#pragma unroll
  for (int v = 0; v < NMOM; ++v) acc[v] = 0.0f;

#pragma unroll
  for (int j = 0; j < K1_ITERS; ++j) {
    const int pt = t + j * K1_STRIDE;
    const int pil = pt >> 5;
    const int m = pt & 31;
    const float4 v = vox[pt];
    const int4 cc = coords[pil];
    const int np = npnts[pil];
    float z = v.z;
#pragma unroll
    for (int s = 1; s < 32; s <<= 1) z += __shfl_xor(z, s, 32);
    const float zc = z * (1.0f / 32.0f);
    float f[9];
    make_f(v, cc, np, m, zc, f);
    int vi = 0;
#pragma unroll
    for (int i = 0; i < 9; ++i) acc[vi++] += f[i];
#pragma unroll
    for (int i = 0; i < 9; ++i)
#pragma unroll
      for (int jj = i; jj < 9; ++jj) acc[vi++] += f[i] * f[jj];
    acc[54] += (m < np) ? 1.0f : 0.0f;
  }

#pragma unroll
  for (int v = 0; v < NMOM; ++v) {
    float x = acc[v];
#pragma unroll
    for (int s = 1; s < 64; s <<= 1) x += __shfl_xor(x, s, 64);
    acc[v] = x;
  }
  __shared__ float red[4][NMOM];
  const int wave = threadIdx.x >> 6, lane = threadIdx.x & 63;
  if (lane == 0) {
#pragma unroll
    for (int v = 0; v < NMOM; ++v) red[wave][v] = acc[v];
  }
  __syncthreads();
  if (threadIdx.x < NMOM) {
    float s = red[0][threadIdx.x] + red[1][threadIdx.x] + red[2][threadIdx.x] + red[3][threadIdx.x];
    P1[threadIdx.x * K1_BLOCKS + blockIdx.x] = s;
  }
}

// ------------------------------------------------- generic row reduce (f32 -> f64)

__global__ __launch_bounds__(256) void k_rowreduce(
    const float* __restrict__ src, double* __restrict__ dst, int ncols) {
  const int row = blockIdx.x;
  const float* p = src + row * ncols;
  double sd = 0.0;
  for (int i = threadIdx.x; i < ncols; i += 256) sd += (double)p[i];
#pragma unroll
  for (int s = 1; s < 64; s <<= 1) sd += __shfl_xor(sd, s, 64);
  __shared__ double rd[4];
  const int wave = threadIdx.x >> 6, lane = threadIdx.x & 63;
  if (lane == 0) rd[wave] = sd;
  __syncthreads();
  if (threadIdx.x == 0) dst[row] = rd[0] + rd[1] + rd[2] + rd[3];
}

// ------------------------------------------------- finalize layer-1 BN params

__global__ void k_fin1(const double* __restrict__ T1, const float* __restrict__ W1,
                       const float* __restrict__ g1, const float* __restrict__ b1,
                       float* __restrict__ params) {
  const int c = threadIdx.x;  // 64
  double w[9];
#pragma unroll
  for (int i = 0; i < 9; ++i) w[i] = (double)W1[i * 64 + c];
  double mean = 0.0;
#pragma unroll
  for (int i = 0; i < 9; ++i) mean += w[i] * T1[i];
  mean /= (double)NPTS;
  double e2 = 0.0;
  int v = 9;
#pragma unroll
  for (int i = 0; i < 9; ++i)
#pragma unroll
    for (int j = i; j < 9; ++j) {
      const double t = T1[v++] * w[i] * w[j];
      e2 += (i == j) ? t : 2.0 * t;
    }
  e2 /= (double)NPTS;
  const double var = e2 - mean * mean;
  const double a = (double)g1[c] / sqrt(var + 0.001);
  params[c] = (float)a;
  params[64 + c] = (float)((double)b1[c] - mean * a);
}

// ------------------------------------------------- K3: layer-2 stats + y2 max/min
// waves_per_eu(2,2): rounds 7/8 showed the allocator TARGETS 4 waves/EU
// regardless of the launch-bounds cap (min-only), demoting w2[64] (VGPR=60,
// +70us of per-use copies/reloads). Setting max=2 tells the scheduler to stop
// optimizing for occupancy >2 and keep w2 in arch VGPRs.

__global__ __attribute__((amdgpu_flat_work_group_size(256, 256)))
__attribute__((amdgpu_waves_per_eu(2, 2))) void k_stats2(
    const float4* __restrict__ vox, const int4* __restrict__ coords,
    const int* __restrict__ npnts, const float* __restrict__ W1,
    const float* __restrict__ W2, const float* __restrict__ params,
    const int* __restrict__ perm, float* __restrict__ P2,
    float* __restrict__ Y2MAX, float* __restrict__ Y2MIN) {
  __shared__ __align__(16) float W1t[9 * 64];
  __shared__ __align__(16) float a1s[64], b1s[64];
  __shared__ __align__(16) float h1s[CHUNK * LDH];
  __shared__ float redS[4][64], redQ[4][64];

  const int t = threadIdx.x;
  for (int i = t; i < 576; i += 256) W1t[i] = W1[i];
  if (t < 64) { a1s[t] = params[t]; b1s[t] = params[64 + t]; }

  const int c = t & 63;
  float w2[64];
#pragma unroll
  for (int k = 0; k < 64; ++k) w2[k] = W2[k * 64 + c];
  __syncthreads();

  const int p_loc = t >> 1;
  const int ch_half = (t & 1) * 32;
  const int g = t >> 6;
  float psum = 0.0f, psq = 0.0f;

  for (int bb = blockIdx.x; bb < NBATCH; bb += SB) {
    // ---- phase A: h1 for 128 points (4 permuted pillars)
    const int pid = perm[bb * 4 + (p_loc >> 5)];
    const int m = p_loc & 31;
    const float4 v = vox[pid * 32 + m];
    const int4 cc = coords[pid];
    const int np = npnts[pid];
    float z = v.z;
#pragma unroll
    for (int s = 1; s < 64; s <<= 1) z += __shfl_xor(z, s, 64);
    const float zc = z * (1.0f / 64.0f);
    float f[9];
    make_f(v, cc, np, m, zc, f);
    float* row = &h1s[p_loc * LDH];
#pragma unroll
    for (int j = 0; j < 8; ++j) {
      const int c0 = ch_half + 4 * j;
      float y0 = 0, y1 = 0, y2 = 0, y3 = 0;
#pragma unroll
      for (int i = 0; i < 9; ++i) {
        const float4 w = *(const float4*)&W1t[i * 64 + c0];
        y0 = fmaf(f[i], w.x, y0);
        y1 = fmaf(f[i], w.y, y1);
        y2 = fmaf(f[i], w.z, y2);
        y3 = fmaf(f[i], w.w, y3);
      }
      const float4 a = *(const float4*)&a1s[c0];
      const float4 b = *(const float4*)&b1s[c0];
      float4 h;
      h.x = fmaxf(fmaf(y0, a.x, b.x), 0.0f);
      h.y = fmaxf(fmaf(y1, a.y, b.y), 0.0f);
      h.z = fmaxf(fmaf(y2, a.z, b.z), 0.0f);
      h.w = fmaxf(fmaf(y3, a.w, b.w), 0.0f);
      *(float4*)&row[c0] = h;
    }
    __syncthreads();
    // ---- phase B: valid points only; track running y2 max/min for this pillar
    const int pidB = perm[bb * 4 + g];
    const int np_g = npnts[pidB];
    float ymx = -INFINITY, ymn = INFINITY;
#pragma unroll 2
    for (int pp = 0; pp < np_g; ++pp) {
      const float4* hr = (const float4*)&h1s[(g * 32 + pp) * LDH];
      float y0 = 0, y1 = 0, y2 = 0, y3 = 0;
#pragma unroll
      for (int a4 = 0; a4 < 16; ++a4) {
        const float4 hv = hr[a4];   // broadcast read
        y0 = fmaf(hv.x, w2[4 * a4 + 0], y0);
        y1 = fmaf(hv.y, w2[4 * a4 + 1], y1);
        y2 = fmaf(hv.z, w2[4 * a4 + 2], y2);
        y3 = fmaf(hv.w, w2[4 * a4 + 3], y3);
      }
      const float y = (y0 + y1) + (y2 + y3);
      psum += y;
      psq = fmaf(y, y, psq);
      ymx = fmaxf(ymx, y);
      ymn = fminf(ymn, y);
    }
    Y2MAX[pidB * 64 + c] = ymx;   // coalesced (lane = channel)
    Y2MIN[pidB * 64 + c] = ymn;
    __syncthreads();
  }

  const int wave = t >> 6;
  redS[wave][c] = psum;
  redQ[wave][c] = psq;
  __syncthreads();
  if (t < 64) {
    const float s = redS[0][t] + redS[1][t] + redS[2][t] + redS[3][t];
    const float q = redQ[0][t] + redQ[1][t] + redQ[2][t] + redQ[3][t];
    P2[t * SB + blockIdx.x] = s;
    P2[(64 + t) * SB + blockIdx.x] = q;
  }
}

// ------------------------------------------------- finalize layer-2 BN params

__global__ void k_fin2(const double* __restrict__ T2, const float* __restrict__ g2,
                       const float* __restrict__ b2, const float* __restrict__ W2,
                       const double* __restrict__ T1, float* __restrict__ params) {
  const int c = threadIdx.x;  // 64
  const double nmask = (double)NPTS - T1[54];
  double y20 = 0.0;
  for (int k = 0; k < 64; ++k) {
    const float h0 = fmaxf(params[64 + k], 0.0f);   // h1_0[k] = relu(b1adj[k])
    y20 += (double)h0 * (double)W2[k * 64 + c];
  }
  const double sum = T2[c] + nmask * y20;
  const double sq  = T2[64 + c] + nmask * y20 * y20;
  const double mean = sum / (double)NPTS;
  const double var = sq / (double)NPTS - mean * mean;
  const double a = (double)g2[c] / sqrt(var + 0.001);
  const double badj = (double)b2[c] - mean * a;
  params[128 + c] = (float)a;
  params[192 + c] = (float)badj;
  params[256 + c] = (float)fmax(a * y20 + badj, 0.0);   // h2_0[c] (relu)
}

// ------------------------------------------------- K5: final output pass.
// h2 = relu(a2*y2 + b2adj) is monotone in y2 (direction = sign(a2)); fma/relu
// rounding is monotone, so max over points = the map applied to max(y2)
// (or min(y2) if a2<0) BIT-EXACTLY. Pure streaming pass, ~37 MB.

__global__ __launch_bounds__(256) void k_final(
    const int* __restrict__ npnts, const float* __restrict__ params,
    const float* __restrict__ Y2MAX, const float* __restrict__ Y2MIN,
    float* __restrict__ out) {
  const int idx = blockIdx.x * 256 + threadIdx.x;   // NPIL*64 total
  const int pid = idx >> 6;
  const int c = idx & 63;
  const int np = npnts[pid];
  const float a2 = params[128 + c];
  const float b2 = params[192 + c];
  const float h20 = params[256 + c];
  const float mx = Y2MAX[idx];
  const float mn = Y2MIN[idx];
  const float sel = (a2 >= 0.0f) ? mx : mn;
  float h = (np > 0) ? fmaxf(fmaf(sel, a2, b2), 0.0f) : 0.0f;
  if (np < 32) h = fmaxf(h, h20);
  out[idx] = h;
}

// ---------------------------------------------------------------- launch

extern "C" void kernel_launch(void* const* d_in, const int* in_sizes, int n_in,
                              void* d_out, int out_size, void* d_ws, size_t ws_size,
                              hipStream_t stream) {
  const float4* vox = (const float4*)d_in[0];
  const int4* coords = (const int4*)d_in[1];
  const int* npnts = (const int*)d_in[2];
  const float* W1 = (const float*)d_in[3];
  const float* g1 = (const float*)d_in[4];
  const float* b1 = (const float*)d_in[5];
  const float* W2 = (const float*)d_in[6];
  const float* g2 = (const float*)d_in[7];
  const float* b2 = (const float*)d_in[8];
  float* out = (float*)d_out;

  char* w = (char*)d_ws;
  size_t off = 0;
  double* T1 = (double*)(w + off); off += 512;                 // 55 doubles
  double* T2 = (double*)(w + off); off += 1024;                // 128 doubles
  float* P1 = (float*)(w + off); off += NMOM * K1_BLOCKS * 4;  // 330 KB
  float* P2 = (float*)(w + off); off += 128 * SB * 4;          // 524 KB
  float* params = (float*)(w + off); off += 512 * 4;           // 320 used
  int* perm = (int*)(w + off); off += NPIL * 4;                // 192 KB
  float* Y2MAX = (float*)(w + off); off += (size_t)NPIL * 64 * 4;  // 12.3 MB
  float* Y2MIN = (float*)(w + off); off += (size_t)NPIL * 64 * 4;  // 12.3 MB

  k_sort<<<1, 256, 0, stream>>>(npnts, perm);
  k_moments<<<K1_BLOCKS, 256, 0, stream>>>(vox, coords, npnts, P1);
  k_rowreduce<<<NMOM, 256, 0, stream>>>(P1, T1, K1_BLOCKS);
  k_fin1<<<1, 64, 0, stream>>>(T1, W1, g1, b1, params);
  k_stats2<<<SB, 256, 0, stream>>>(vox, coords, npnts, W1, W2, params, perm, P2, Y2MAX, Y2MIN);
  k_rowreduce<<<128, 256, 0, stream>>>(P2, T2, SB);
  k_fin2<<<1, 64, 0, stream>>>(T2, g2, b2, W2, T1, params);
  k_final<<<(NPIL * 64) / 256, 256, 0, stream>>>(npnts, params, Y2MAX, Y2MIN, out);
}